// Round 4
// baseline (31.451 us; speedup 1.0000x reference)
//
#include <hip/hip_runtime.h>

#define NN 65536
#define DD 8
#define LATD 64
#define HIDD 128
#define FEATD 16
#define BPD 96            // k_mlp blocks per decoder (768 total = 3/CU)
#define SXS 72            // sX stride (u16): 144 B = 9 quads (odd -> conflict-free)
#define SHS 136           // sH stride (u16): 272 B = 17 quads (odd -> conflict-free)

typedef __attribute__((ext_vector_type(8))) short short8;
typedef __attribute__((ext_vector_type(4))) float f32x4;
typedef __attribute__((ext_vector_type(8))) unsigned short ushort8;

static __device__ __forceinline__ unsigned short f2bf(float f) {
  union { float f; unsigned u; } v; v.f = f;
  unsigned r = v.u + 0x7FFFu + ((v.u >> 16) & 1u);  // RNE; exact for small ints
  return (unsigned short)(r >> 16);
}

// ---- prep: blocks [0,256) bucket entries; blocks [256,768) convert scales --
__global__ __launch_bounds__(256) void k_prep(
    const float* __restrict__ ap, int* __restrict__ cursor,
    unsigned short* __restrict__ perm,
    const float* __restrict__ s0, const float* __restrict__ s1,
    const float* __restrict__ s2,
    unsigned short* __restrict__ g0, unsigned short* __restrict__ g1,
    unsigned short* __restrict__ g2) {
  int bid = blockIdx.x;
  int t = threadIdx.x;
  if (bid < 256) {
    // ---- bucket: argmax over D + scatter into per-decoder perm lists ----
    __shared__ int bc[DD];
    __shared__ int bbase[DD];
    if (t < DD) bc[t] = 0;
    __syncthreads();
    int n = bid * 256 + t;
    float best = ap[n];
    int bd = 0;
#pragma unroll
    for (int d = 1; d < DD; ++d) {
      float v = ap[d * NN + n];
      if (v > best) { best = v; bd = d; }  // strict >: first max (jnp.argmax)
    }
    int lr = atomicAdd(&bc[bd], 1);
    __syncthreads();
    if (t < DD) bbase[t] = atomicAdd(&cursor[t], bc[t]);
    __syncthreads();
    perm[bd * NN + bbase[bd] + lr] = (unsigned short)n;
  } else {
    // ---- convert scales to bf16, transposed to [d][n][k] ----
    int o = (bid - 256) * 256 + t;
    if (o < DD * HIDD * LATD) {            // g0[d][n(128)][k(64)] <- s0[d][k][n]
      int d = o >> 13, rem = o & 8191, n = rem >> 6, k = rem & 63;
      g0[o] = f2bf(s0[d * 8192 + k * 128 + n]);
    }
    if (o < DD * HIDD * HIDD) {            // g1[d][n(128)][k(128)] <- s1[d][k][n]
      int d = o >> 14, rem = o & 16383, n = rem >> 7, k = rem & 127;
      g1[o] = f2bf(s1[d * 16384 + k * 128 + n]);
    }
    if (o < DD * FEATD * HIDD) {           // g2[d][n(16)][k(128)] <- s2[d][k][n]
      int d = o >> 11, rem = o & 2047, n = rem >> 7, k = rem & 127;
      g2[o] = f2bf(s2[d * 2048 + k * 16 + n]);
    }
  }
}

// ---- fused 3-layer MLP: B-fragments in registers, H through LDS -----------
// 256 thr = 4 waves; tile = 64 entries. Wave w owns output col-blocks
// {2w, 2w+1} (16 cols each) for L1/L2; L3 row-group = w.
__global__ __launch_bounds__(256, 3) void k_mlp(
    const float* __restrict__ weight, const float* __restrict__ divv,
    const unsigned short* __restrict__ g0, const float* __restrict__ sh0,
    const unsigned short* __restrict__ g1, const float* __restrict__ sh1,
    const unsigned short* __restrict__ g2, const float* __restrict__ sh2,
    const int* __restrict__ cursor, const unsigned short* __restrict__ perm,
    float* __restrict__ out) {
  __shared__ unsigned short sX[64 * SXS];   // X  [entry][k=64] bf16
  __shared__ unsigned short sH1[64 * SHS];  // H1 [entry][k=128] bf16
  __shared__ unsigned short sH2[64 * SHS];  // H2 [entry][k=128] bf16
  __shared__ unsigned short sP[64];         // perm cache for this tile

  int d = blockIdx.x / BPD, bslot = blockIdx.x % BPD;
  int cnt = cursor[d];
  int t = threadIdx.x;
  int w = t >> 6, l = t & 63;
  int lrow = l & 15, kgrp = l >> 4;

  // ---- load B fragments (contiguous bf16) once per block ----
  short8 b0[2][2];  // [cb][ks] layer1 (k=64)
  short8 b1[2][4];  // [cb][ks] layer2 (k=128)
  short8 b2[4];     // [ks]     layer3 (k=128, 16 cols)
  float sh0v[2], sh1v[2];
  const unsigned short* G0 = g0 + d * (HIDD * LATD);
  const unsigned short* G1 = g1 + d * (HIDD * HIDD);
  const unsigned short* G2 = g2 + d * (FEATD * HIDD);
#pragma unroll
  for (int cb = 0; cb < 2; ++cb) {
    int n = (2 * w + cb) * 16 + lrow;
#pragma unroll
    for (int ks = 0; ks < 2; ++ks)
      b0[cb][ks] = *(const short8*)&G0[n * LATD + ks * 32 + kgrp * 8];
#pragma unroll
    for (int ks = 0; ks < 4; ++ks)
      b1[cb][ks] = *(const short8*)&G1[n * HIDD + ks * 32 + kgrp * 8];
    sh0v[cb] = sh0[d * HIDD + n];
    sh1v[cb] = sh1[d * HIDD + n];
  }
#pragma unroll
  for (int ks = 0; ks < 4; ++ks)
    b2[ks] = *(const short8*)&G2[lrow * HIDD + ks * 32 + kgrp * 8];
  float sh2v = sh2[d * FEATD + lrow];

  for (int tile = bslot; tile * 64 < cnt; tile += BPD) {
    int base = tile * 64;

    // ---- stage X = rint(weight)/div into sX (4 threads per entry row) ----
    {
      int r = t >> 2, c = t & 3;
      int gp = base + r;
      unsigned short pe = 0;
      short8 lo = {0, 0, 0, 0, 0, 0, 0, 0}, hi = {0, 0, 0, 0, 0, 0, 0, 0};
      if (gp < cnt) {
        pe = perm[d * NN + gp];
        const float* wr = weight + (int)pe * LATD + c * 16;
        const float* dv = divv + c * 16;
#pragma unroll
        for (int q = 0; q < 2; ++q) {
          float4 f = *(const float4*)(wr + q * 4);
          float4 g = *(const float4*)(dv + q * 4);
          lo[q * 4 + 0] = (short)f2bf(rintf(f.x) / g.x);
          lo[q * 4 + 1] = (short)f2bf(rintf(f.y) / g.y);
          lo[q * 4 + 2] = (short)f2bf(rintf(f.z) / g.z);
          lo[q * 4 + 3] = (short)f2bf(rintf(f.w) / g.w);
        }
#pragma unroll
        for (int q = 0; q < 2; ++q) {
          float4 f = *(const float4*)(wr + 8 + q * 4);
          float4 g = *(const float4*)(dv + 8 + q * 4);
          hi[q * 4 + 0] = (short)f2bf(rintf(f.x) / g.x);
          hi[q * 4 + 1] = (short)f2bf(rintf(f.y) / g.y);
          hi[q * 4 + 2] = (short)f2bf(rintf(f.z) / g.z);
          hi[q * 4 + 3] = (short)f2bf(rintf(f.w) / g.w);
        }
      }
      if (c == 0) sP[r] = pe;
      *(short8*)&sX[r * SXS + c * 16] = lo;
      *(short8*)&sX[r * SXS + c * 16 + 8] = hi;
    }
    __syncthreads();

    // perm rows for this wave's L3 stores (sP stable: next stage is behind
    // barriers 2 & 3)
    int prow[4];
#pragma unroll
    for (int rr = 0; rr < 4; ++rr) prow[rr] = (int)sP[w * 16 + kgrp * 4 + rr];

    // ---- layer 1: [64]->[128] relu, sX -> sH1 ----
#pragma unroll
    for (int rg = 0; rg < 4; ++rg) {
      short8 a0 = *(short8*)&sX[(rg * 16 + lrow) * SXS + kgrp * 8];
      short8 a1 = *(short8*)&sX[(rg * 16 + lrow) * SXS + 32 + kgrp * 8];
      __builtin_amdgcn_s_setprio(1);
#pragma unroll
      for (int cb = 0; cb < 2; ++cb) {
        f32x4 acc = {sh0v[cb], sh0v[cb], sh0v[cb], sh0v[cb]};
        acc = __builtin_amdgcn_mfma_f32_16x16x32_bf16(a0, b0[cb][0], acc, 0, 0, 0);
        acc = __builtin_amdgcn_mfma_f32_16x16x32_bf16(a1, b0[cb][1], acc, 0, 0, 0);
#pragma unroll
        for (int rr = 0; rr < 4; ++rr)
          sH1[(rg * 16 + kgrp * 4 + rr) * SHS + (2 * w + cb) * 16 + lrow] =
              f2bf(fmaxf(acc[rr], 0.f));
      }
      __builtin_amdgcn_s_setprio(0);
    }
    __syncthreads();

    // ---- layer 2: [128]->[128] relu, sH1 -> sH2 ----
#pragma unroll
    for (int rg = 0; rg < 4; ++rg) {
      short8 h0 = *(short8*)&sH1[(rg * 16 + lrow) * SHS + kgrp * 8];
      short8 h1 = *(short8*)&sH1[(rg * 16 + lrow) * SHS + 32 + kgrp * 8];
      short8 h2 = *(short8*)&sH1[(rg * 16 + lrow) * SHS + 64 + kgrp * 8];
      short8 h3 = *(short8*)&sH1[(rg * 16 + lrow) * SHS + 96 + kgrp * 8];
      __builtin_amdgcn_s_setprio(1);
#pragma unroll
      for (int cb = 0; cb < 2; ++cb) {
        f32x4 acc = {sh1v[cb], sh1v[cb], sh1v[cb], sh1v[cb]};
        acc = __builtin_amdgcn_mfma_f32_16x16x32_bf16(h0, b1[cb][0], acc, 0, 0, 0);
        acc = __builtin_amdgcn_mfma_f32_16x16x32_bf16(h1, b1[cb][1], acc, 0, 0, 0);
        acc = __builtin_amdgcn_mfma_f32_16x16x32_bf16(h2, b1[cb][2], acc, 0, 0, 0);
        acc = __builtin_amdgcn_mfma_f32_16x16x32_bf16(h3, b1[cb][3], acc, 0, 0, 0);
#pragma unroll
        for (int rr = 0; rr < 4; ++rr)
          sH2[(rg * 16 + kgrp * 4 + rr) * SHS + (2 * w + cb) * 16 + lrow] =
              f2bf(fmaxf(acc[rr], 0.f));
      }
      __builtin_amdgcn_s_setprio(0);
    }
    __syncthreads();

    // ---- layer 3: [128]->[16], row-group = wave, store via perm ----
    {
      short8 q0 = *(short8*)&sH2[(w * 16 + lrow) * SHS + kgrp * 8];
      short8 q1 = *(short8*)&sH2[(w * 16 + lrow) * SHS + 32 + kgrp * 8];
      short8 q2 = *(short8*)&sH2[(w * 16 + lrow) * SHS + 64 + kgrp * 8];
      short8 q3 = *(short8*)&sH2[(w * 16 + lrow) * SHS + 96 + kgrp * 8];
      f32x4 acc = {sh2v, sh2v, sh2v, sh2v};
      __builtin_amdgcn_s_setprio(1);
      acc = __builtin_amdgcn_mfma_f32_16x16x32_bf16(q0, b2[0], acc, 0, 0, 0);
      acc = __builtin_amdgcn_mfma_f32_16x16x32_bf16(q1, b2[1], acc, 0, 0, 0);
      acc = __builtin_amdgcn_mfma_f32_16x16x32_bf16(q2, b2[2], acc, 0, 0, 0);
      acc = __builtin_amdgcn_mfma_f32_16x16x32_bf16(q3, b2[3], acc, 0, 0, 0);
      __builtin_amdgcn_s_setprio(0);
#pragma unroll
      for (int rr = 0; rr < 4; ++rr) {
        int row = w * 16 + kgrp * 4 + rr;
        if (base + row < cnt) out[prow[rr] * FEATD + lrow] = acc[rr];
      }
    }
  }
}

// ---------------------------------------------------------------------------
extern "C" void kernel_launch(void* const* d_in, const int* in_sizes, int n_in,
                              void* d_out, int out_size, void* d_ws, size_t ws_size,
                              hipStream_t stream) {
  const float* weight      = (const float*)d_in[0];
  const float* alpha_param = (const float*)d_in[1];
  const float* divv        = (const float*)d_in[2];
  const float* scale0      = (const float*)d_in[3];
  const float* shift0      = (const float*)d_in[4];
  const float* scale1      = (const float*)d_in[5];
  const float* shift1      = (const float*)d_in[6];
  const float* scale2      = (const float*)d_in[7];
  const float* shift2      = (const float*)d_in[8];
  float* out = (float*)d_out;

  int* cursor = (int*)d_ws;                                   // [8]
  unsigned short* perm = (unsigned short*)((int*)d_ws + 8);   // [8][N]
  unsigned short* g0 = perm + DD * NN;                        // [8][128][64]
  unsigned short* g1 = g0 + DD * HIDD * LATD;                 // [8][128][128]
  unsigned short* g2 = g1 + DD * HIDD * HIDD;                 // [8][16][128]

  hipMemsetAsync(cursor, 0, DD * sizeof(int), stream);
  k_prep<<<256 + 512, 256, 0, stream>>>(alpha_param, cursor, perm,
                                        scale0, scale1, scale2, g0, g1, g2);
  k_mlp<<<DD * BPD, 256, 0, stream>>>(weight, divv,
                                      g0, shift0, g1, shift1, g2, shift2,
                                      cursor, perm, out);
}